// Round 7
// baseline (112.931 us; speedup 1.0000x reference)
//
#include <hip/hip_runtime.h>
#include <hip/hip_bf16.h>
#include <math.h>

#define NP 1024          // proposals
#define NC 81            // classes incl background
#define CF 80            // foreground classes
#define DET 100          // detections per image
#define SCORE_THRESH 0.05f
#define NMS_THRESH 0.5f
#define BBOX_CLIP 4.135166556742356f   // log(1000/16)
#define IMG_W 1333
#define IMG_H 800

#define NCAND (CF * DET)   // 8000 max compacted candidates
#define MAGIC 0x13579BDFu  // != 0xAAAAAAAA poison; flags need no pre-init

#define NSOFT 256          // softmax producer blocks (4 proposals each)
#define NTOPK 32           // topk blocks (32*256 = 8192 >= NCAND lanes)
// grid = NSOFT + CF + NTOPK = 368 blocks * 256 thr; worst-case LDS 64.1 KB
// -> 2 blocks/CU -> 512 resident slots >= 368: ALL blocks co-resident by
// capacity, so flag spin-waits cannot deadlock (no dispatch-order assumption).

struct NmsShared {
    unsigned long long key[NP];
    float4             vbox[NP];
    unsigned char      supp[NP];
    int                cntSh;
    int                keptRank[DET];
    int                keptCnt;
    int                baseSh;
};
struct TopkShared {
    unsigned long long keysh[NCAND + 16];
};
#define SH_BYTES (sizeof(TopkShared) > sizeof(NmsShared) ? sizeof(TopkShared) : sizeof(NmsShared))

__device__ __forceinline__ void flag_set(unsigned int* f) {
    __hip_atomic_store(f, MAGIC, __ATOMIC_RELEASE, __HIP_MEMORY_SCOPE_AGENT);
}
__device__ __forceinline__ void flag_spin(const unsigned int* f) {
    while (__hip_atomic_load(f, __ATOMIC_RELAXED, __HIP_MEMORY_SCOPE_AGENT) != MAGIC) {}
}
__device__ __forceinline__ void flag_acquire(const unsigned int* f) {
    (void)__hip_atomic_load(f, __ATOMIC_ACQUIRE, __HIP_MEMORY_SCOPE_AGENT);
}

// ---------------------------------------------------------------------------
// One fused kernel: softmax producers -> per-class NMS -> global top-100,
// linked by device-scope MAGIC flags. All float math verbatim from the
// absmax-0.0 R6 kernels.
// ---------------------------------------------------------------------------
__global__ __launch_bounds__(256) void
fused_postprocess_kernel(const float* __restrict__ logits,
                         const float* __restrict__ rel,
                         const float* __restrict__ props,
                         float* __restrict__ scores_fg,
                         unsigned long long* __restrict__ gkeys,
                         float4* __restrict__ gboxes,
                         int* __restrict__ gK,
                         unsigned int* __restrict__ done1,   // [NSOFT]
                         unsigned int* __restrict__ done2,   // [CF]
                         float* __restrict__ out) {
    __shared__ __align__(16) unsigned char shraw[SH_BYTES];
    const int bid = blockIdx.x;
    const int tid = threadIdx.x;

    // ======================= role 1: softmax producers ======================
    if (bid < NSOFT) {
        if (bid == 0 && tid == 0) *gK = 0;   // ordered before flag release

        const int wave = tid >> 6;
        const int lane = tid & 63;
        const int i = bid * 4 + wave;        // proposal index

        const float x0 = logits[i * NC + lane];
        const float x1 = (lane < NC - 64) ? logits[i * NC + 64 + lane] : -INFINITY;

        float m = fmaxf(x0, x1);
        for (int off = 32; off > 0; off >>= 1) m = fmaxf(m, __shfl_xor(m, off));

        const float e0 = expf(x0 - m);
        const float e1 = (lane < NC - 64) ? expf(x1 - m) : 0.0f;
        float sum = e0 + e1;
        for (int off = 32; off > 0; off >>= 1) sum += __shfl_xor(sum, off);

        if (lane >= 1) scores_fg[(lane - 1) * NP + i] = e0 / sum;
        if (lane < NC - 64) scores_fg[(64 + lane - 1) * NP + i] = e1 / sum;

        __syncthreads();                      // drains all waves' vmem stores
        if (tid == 0) flag_set(&done1[bid]);  // release: wbl2 pushes them out
        return;
    }

    // ========================= role 2: per-class NMS ========================
    if (bid < NSOFT + CF) {
        const int cls = bid - NSOFT;          // fg class (reference = cls+1)
        NmsShared& S = *(NmsShared*)shraw;

        if (tid == 0) S.cntSh = 0;
        flag_spin(&done1[tid]);               // thread t waits on producer t
        __syncthreads();
        flag_acquire(&done1[0]);              // every thread: invalidate caches

        // threshold compaction: 1024 scores, one float4 per thread
        {
            const float4 v = ((const float4*)(scores_fg + cls * NP))[tid];
            const int id0 = tid * 4;
            if (v.x > SCORE_THRESH) { int p = atomicAdd(&S.cntSh, 1); S.key[p] = ((unsigned long long)__float_as_uint(v.x) << 16) | (unsigned long long)(1023 - (id0 + 0)); }
            if (v.y > SCORE_THRESH) { int p = atomicAdd(&S.cntSh, 1); S.key[p] = ((unsigned long long)__float_as_uint(v.y) << 16) | (unsigned long long)(1023 - (id0 + 1)); }
            if (v.z > SCORE_THRESH) { int p = atomicAdd(&S.cntSh, 1); S.key[p] = ((unsigned long long)__float_as_uint(v.z) << 16) | (unsigned long long)(1023 - (id0 + 2)); }
            if (v.w > SCORE_THRESH) { int p = atomicAdd(&S.cntSh, 1); S.key[p] = ((unsigned long long)__float_as_uint(v.w) << 16) | (unsigned long long)(1023 - (id0 + 3)); }
        }
        __syncthreads();
        const int cnt = S.cntSh;

        int msz = 1;
        while (msz < cnt) msz <<= 1;
        for (int t = cnt + tid; t < msz; t += 256) S.key[t] = 0ull;
        __syncthreads();

        // bitonic sort descending (u64 key encodes score desc, id asc)
        for (int k = 2; k <= msz; k <<= 1) {
            for (int jj = k >> 1; jj > 0; jj >>= 1) {
                for (int t = tid; t < msz; t += 256) {
                    const int ixj = t ^ jj;
                    if (ixj > t) {
                        const unsigned long long a = S.key[t], b = S.key[ixj];
                        const bool tAfter = (a < b);
                        const bool dirAsc = ((t & k) == 0);
                        if (dirAsc ? tAfter : !tAfter) { S.key[t] = b; S.key[ixj] = a; }
                    }
                }
                __syncthreads();
            }
        }

        // on-demand box decode for survivors (exact reference formulas)
        for (int t = tid; t < cnt; t += 256) {
            const int id = 1023 - (int)(S.key[t] & 0xFFFFull);
            const float4 p = ((const float4*)props)[id];
            const float w  = p.z - p.x + 1.0f;
            const float h  = p.w - p.y + 1.0f;
            const float cx = p.x + 0.5f * w;
            const float cy = p.y + 0.5f * h;

            const float4 r = ((const float4*)rel)[id * NC + (cls + 1)];
            const float dx = r.x / 10.0f;
            const float dy = r.y / 10.0f;
            const float dw = fminf(r.z / 5.0f, BBOX_CLIP);
            const float dh = fminf(r.w / 5.0f, BBOX_CLIP);

            const float pcx = dx * w + cx;
            const float pcy = dy * h + cy;
            const float pw  = expf(dw) * w;
            const float ph  = expf(dh) * h;

            float bx1 = pcx - 0.5f * pw;
            float by1 = pcy - 0.5f * ph;
            float bx2 = pcx + 0.5f * pw - 1.0f;
            float by2 = pcy + 0.5f * ph - 1.0f;

            bx1 = fminf(fmaxf(bx1, 0.0f), (float)(IMG_W - 1));
            bx2 = fminf(fmaxf(bx2, 0.0f), (float)(IMG_W - 1));
            by1 = fminf(fmaxf(by1, 0.0f), (float)(IMG_H - 1));
            by2 = fminf(fmaxf(by2, 0.0f), (float)(IMG_H - 1));

            S.vbox[t] = make_float4(bx1, by1, bx2, by2);
            S.supp[t] = 0;
        }
        __syncthreads();

        if (cnt <= 64) {
            // fast NMS: per-lane suppression bitmask + scalar ballot resolve
            unsigned long long mymask = 0ull;
            if (tid < cnt) {
                const float4 bj = S.vbox[tid];
                const float areaj = (bj.z - bj.x + 1.0f) * (bj.w - bj.y + 1.0f);
                for (int i = 0; i < tid; ++i) {
                    const float4 bi = S.vbox[i];
                    const float areai = (bi.z - bi.x + 1.0f) * (bi.w - bi.y + 1.0f);
                    const float ltx = fmaxf(bi.x, bj.x);
                    const float lty = fmaxf(bi.y, bj.y);
                    const float rbx = fminf(bi.z, bj.z);
                    const float rby = fminf(bi.w, bj.w);
                    const float wq = fmaxf(rbx - ltx + 1.0f, 0.0f);
                    const float hq = fmaxf(rby - lty + 1.0f, 0.0f);
                    const float inter = wq * hq;
                    const float iou = inter / (areai + areaj - inter);
                    if (iou > NMS_THRESH) mymask |= (1ull << i);
                }
            }
            unsigned long long suppbits = 0ull;
            for (int i = 0; i < cnt; ++i) {
                if (!((suppbits >> i) & 1ull)) {
                    const unsigned long long vote = __ballot((mymask >> i) & 1ull);
                    suppbits |= vote;
                }
            }
            if (tid < cnt) S.supp[tid] = (unsigned char)((suppbits >> tid) & 1ull);
            __syncthreads();
        } else {
            for (int i = 0; i < cnt; ++i) {
                if (!S.supp[i]) {
                    const float4 bi = S.vbox[i];
                    const float areai = (bi.z - bi.x + 1.0f) * (bi.w - bi.y + 1.0f);
                    for (int t = i + 1 + tid; t < cnt; t += 256) {
                        const float4 bj = S.vbox[t];
                        const float areaj = (bj.z - bj.x + 1.0f) * (bj.w - bj.y + 1.0f);
                        const float ltx = fmaxf(bi.x, bj.x);
                        const float lty = fmaxf(bi.y, bj.y);
                        const float rbx = fminf(bi.z, bj.z);
                        const float rby = fminf(bi.w, bj.w);
                        const float wq = fmaxf(rbx - ltx + 1.0f, 0.0f);
                        const float hq = fmaxf(rby - lty + 1.0f, 0.0f);
                        const float inter = wq * hq;
                        const float iou = inter / (areai + areaj - inter);
                        if (iou > NMS_THRESH) S.supp[t] = 1;
                    }
                }
                __syncthreads();
            }
        }

        if (tid == 0) {
            int c2 = 0;
            for (int r = 0; r < cnt && c2 < DET; ++r)
                if (!S.supp[r]) S.keptRank[c2++] = r;
            S.keptCnt = c2;
            S.baseSh = atomicAdd(gK, c2);   // device-scope dense append
        }
        __syncthreads();

        const int kc = S.keptCnt, base = S.baseSh;
        for (int t = tid; t < kc; t += 256) {
            const int r = S.keptRank[t];
            const int slot = cls * DET + t;
            const unsigned int bits = (unsigned int)(S.key[r] >> 16);
            gkeys[base + t] = ((unsigned long long)bits << 16) |
                              (unsigned long long)(65535 - slot);
            gboxes[base + t] = S.vbox[r];
        }

        __syncthreads();                      // drain stores before release
        if (tid == 0) flag_set(&done2[cls]);
        return;
    }

    // =========================== role 3: top-k ==============================
    {
        const int tb = bid - NSOFT - CF;      // 0..NTOPK-1
        TopkShared& T = *(TopkShared*)shraw;

        if (tid < CF) flag_spin(&done2[tid]);
        __syncthreads();
        flag_acquire(&done2[0]);              // every thread: invalidate caches

        const int K = *gK;
        const int Kc = (K < DET) ? K : DET;

        // zero-tail: out is written ONLY by topk blocks (no cross-role race)
        if (tb == 0) {
            for (int r = Kc + tid; r < DET; r += 256) {
                out[r * 4 + 0] = 0.0f; out[r * 4 + 1] = 0.0f;
                out[r * 4 + 2] = 0.0f; out[r * 4 + 3] = 0.0f;
                out[4 * DET + r] = 0.0f;
                out[5 * DET + r] = 0.0f;
            }
        }
        if (tb * 256 >= K) return;

        const int Kpad = (K + 15) & ~15;
        for (int t = tid; t < Kpad; t += 256)
            T.keysh[t] = (t < K) ? gkeys[t] : 0ull;
        __syncthreads();

        const int g = tb * 256 + tid;
        if (g >= K) return;
        const unsigned long long my = T.keysh[g];

        const ulonglong2* kp = (const ulonglong2*)T.keysh;
        const int nb2 = Kpad >> 1;            // multiple of 8
        int rank = 0;
        for (int j = 0; j < nb2; j += 8) {
            ulonglong2 kk[8];
            #pragma unroll
            for (int u = 0; u < 8; ++u) kk[u] = kp[j + u];
            #pragma unroll
            for (int u = 0; u < 8; ++u) {
                rank += (kk[u].x > my) ? 1 : 0;
                rank += (kk[u].y > my) ? 1 : 0;
            }
        }

        if (rank < DET) {
            const float sc  = __uint_as_float((unsigned)(my >> 16));
            const int  slot = 65535 - (int)(my & 0xFFFFull);
            const float4 b = gboxes[g];
            out[rank * 4 + 0] = b.x;
            out[rank * 4 + 1] = b.y;
            out[rank * 4 + 2] = b.z;
            out[rank * 4 + 3] = b.w;
            out[4 * DET + rank] = sc;
            out[5 * DET + rank] = (float)(slot / DET + 1);
        }
    }
}

// ---------------------------------------------------------------------------
extern "C" void kernel_launch(void* const* d_in, const int* in_sizes, int n_in,
                              void* d_out, int out_size, void* d_ws, size_t ws_size,
                              hipStream_t stream) {
    (void)in_sizes; (void)n_in; (void)out_size; (void)ws_size;

    const float* class_logits   = (const float*)d_in[0];  // [NP, NC]
    const float* box_regression = (const float*)d_in[1];  // [NP, 4*NC]
    const float* proposals      = (const float*)d_in[2];  // [NP, 4]
    float* out = (float*)d_out;                           // 600 floats

    // Workspace layout (float units; all offsets 16B-aligned)
    float* ws        = (float*)d_ws;
    float* gboxes_f  = ws;                                    // NCAND*4 = 32000
    float* gkeys_f   = gboxes_f + (size_t)NCAND * 4;          // NCAND*2 = 16000
    float* scores_fg = gkeys_f + (size_t)NCAND * 2;           // CF*NP   = 81920
    int*   gK        = (int*)(scores_fg + (size_t)CF * NP);   // 4 ints pad
    unsigned int* done1 = (unsigned int*)(gK + 4);            // NSOFT u32
    unsigned int* done2 = done1 + NSOFT;                      // CF u32

    unsigned long long* gkeys = (unsigned long long*)gkeys_f;
    float4* gboxes = (float4*)gboxes_f;

    fused_postprocess_kernel<<<dim3(NSOFT + CF + NTOPK), dim3(256), 0, stream>>>(
        class_logits, box_regression, proposals,
        scores_fg, gkeys, gboxes, gK, done1, done2, out);
}

// Round 8
// 92.799 us; speedup vs baseline: 1.2169x; 1.2169x over previous
//
#include <hip/hip_runtime.h>
#include <hip/hip_bf16.h>
#include <math.h>

#define NP 1024          // proposals
#define NC 81            // classes incl background
#define CF 80            // foreground classes
#define DET 100          // detections per image
#define SCORE_THRESH 0.05f
#define NMS_THRESH 0.5f
#define BBOX_CLIP 4.135166556742356f   // log(1000/16)
#define IMG_W 1333
#define IMG_H 800

#define NCAND (CF * DET)   // 8000 max compacted candidates

// ---------------------------------------------------------------------------
// Kernel 1: per-proposal softmax scores. One wave per proposal, 4/block.
// scores_fg class-major [c][i]. Block 0 zeroes d_out and gK.
// (Float op association proven bit-exact vs reference: absmax 0.0 R1..R7.)
// ---------------------------------------------------------------------------
__global__ __launch_bounds__(256) void
softmax_kernel(const float* __restrict__ logits,
               float* __restrict__ scores_fg,
               float* __restrict__ out,
               int* __restrict__ gK) {
    if (blockIdx.x == 0) {
        for (int t = threadIdx.x; t < 6 * DET; t += 256) out[t] = 0.0f;
        if (threadIdx.x == 0) *gK = 0;
    }

    const int wave = threadIdx.x >> 6;
    const int lane = threadIdx.x & 63;
    const int i = blockIdx.x * 4 + wave;          // proposal index

    const float x0 = logits[i * NC + lane];
    const float x1 = (lane < NC - 64) ? logits[i * NC + 64 + lane] : -INFINITY;

    float m = fmaxf(x0, x1);
    for (int off = 32; off > 0; off >>= 1) m = fmaxf(m, __shfl_xor(m, off));

    const float e0 = expf(x0 - m);
    const float e1 = (lane < NC - 64) ? expf(x1 - m) : 0.0f;
    float sum = e0 + e1;
    for (int off = 32; off > 0; off >>= 1) sum += __shfl_xor(sum, off);

    if (lane >= 1) scores_fg[(lane - 1) * NP + i] = e0 / sum;
    if (lane < NC - 64) scores_fg[(64 + lane - 1) * NP + i] = e1 / sum;
}

// ---------------------------------------------------------------------------
// Kernel 2: per-class threshold-compact -> sort -> decode -> NMS -> append.
// Fast path (cnt<=64, the actual data regime): 2-barrier rank-placement sort
// (keys unique -> ranks are a perfect permutation), ballot-bitmask NMS, and
// popcount compaction — no serial tid0 work, ~6 barriers total.
// Slow path (cnt>64): R6's bitonic + barrier-NMS + serial compact, verbatim.
// Key = (score_bits<<16)|(65535-slot), slot = cls*DET + keptRank: order-
// isomorphic to the reference's (score desc, flat-index asc) tie-break.
// ---------------------------------------------------------------------------
__global__ __launch_bounds__(64) void
class_nms_kernel(const float* __restrict__ scores_fg,
                 const float* __restrict__ rel,
                 const float* __restrict__ props,
                 unsigned long long* __restrict__ gkeys,
                 float4* __restrict__ gboxes,
                 int* __restrict__ gK) {
    const int cls = blockIdx.x;   // fg class (reference class = cls+1)
    const int tid = threadIdx.x;  // 0..63

    __shared__ unsigned long long key[NP];
    __shared__ float4             vbox[NP];
    __shared__ unsigned char      supp[NP];
    __shared__ int                cntSh;
    __shared__ int                keptRank[DET];
    __shared__ int                keptCnt;
    __shared__ int                baseSh;

    if (tid == 0) cntSh = 0;
    __syncthreads();

    // threshold compaction: 1024 scores, 4 float4 per lane
    const float4* srow = (const float4*)(scores_fg + cls * NP);
    #pragma unroll
    for (int k = 0; k < 4; ++k) {
        const int idx4 = k * 64 + tid;
        const float4 v = srow[idx4];
        const int id0 = idx4 * 4;
        if (v.x > SCORE_THRESH) { int p = atomicAdd(&cntSh, 1); key[p] = ((unsigned long long)__float_as_uint(v.x) << 16) | (unsigned long long)(1023 - (id0 + 0)); }
        if (v.y > SCORE_THRESH) { int p = atomicAdd(&cntSh, 1); key[p] = ((unsigned long long)__float_as_uint(v.y) << 16) | (unsigned long long)(1023 - (id0 + 1)); }
        if (v.z > SCORE_THRESH) { int p = atomicAdd(&cntSh, 1); key[p] = ((unsigned long long)__float_as_uint(v.z) << 16) | (unsigned long long)(1023 - (id0 + 2)); }
        if (v.w > SCORE_THRESH) { int p = atomicAdd(&cntSh, 1); key[p] = ((unsigned long long)__float_as_uint(v.w) << 16) | (unsigned long long)(1023 - (id0 + 3)); }
    }
    __syncthreads();
    const int cnt = cntSh;
    if (cnt == 0) return;   // wave-uniform; nothing to append

    if (cnt <= 64) {
        // ================== FAST PATH: single-wave, cnt<=64 ==================
        // rank-placement sort (desc): rank = #{key_j > mine}; unique keys ->
        // perfect permutation. LDS broadcast reads, 2 barriers.
        unsigned long long my = 0ull;
        int rk = 0;
        if (tid < cnt) {
            my = key[tid];
            for (int i = 0; i < cnt; ++i) rk += (key[i] > my) ? 1 : 0;
        }
        __syncthreads();
        if (tid < cnt) key[rk] = my;
        __syncthreads();

        // on-demand box decode (exact reference formulas), one lane per cand
        if (tid < cnt) {
            const int id = 1023 - (int)(key[tid] & 0xFFFFull);
            const float4 p = ((const float4*)props)[id];
            const float w  = p.z - p.x + 1.0f;
            const float h  = p.w - p.y + 1.0f;
            const float cx = p.x + 0.5f * w;
            const float cy = p.y + 0.5f * h;

            const float4 r = ((const float4*)rel)[id * NC + (cls + 1)];
            const float dx = r.x / 10.0f;
            const float dy = r.y / 10.0f;
            const float dw = fminf(r.z / 5.0f, BBOX_CLIP);
            const float dh = fminf(r.w / 5.0f, BBOX_CLIP);

            const float pcx = dx * w + cx;
            const float pcy = dy * h + cy;
            const float pw  = expf(dw) * w;
            const float ph  = expf(dh) * h;

            float bx1 = pcx - 0.5f * pw;
            float by1 = pcy - 0.5f * ph;
            float bx2 = pcx + 0.5f * pw - 1.0f;
            float by2 = pcy + 0.5f * ph - 1.0f;

            bx1 = fminf(fmaxf(bx1, 0.0f), (float)(IMG_W - 1));
            bx2 = fminf(fmaxf(bx2, 0.0f), (float)(IMG_W - 1));
            by1 = fminf(fmaxf(by1, 0.0f), (float)(IMG_H - 1));
            by2 = fminf(fmaxf(by2, 0.0f), (float)(IMG_H - 1));

            vbox[tid] = make_float4(bx1, by1, bx2, by2);
        }
        __syncthreads();

        // NMS: per-lane "suppressed-by-leader-i" bitmask + ballot resolve
        unsigned long long mymask = 0ull;
        if (tid < cnt) {
            const float4 bj = vbox[tid];
            const float areaj = (bj.z - bj.x + 1.0f) * (bj.w - bj.y + 1.0f);
            for (int i = 0; i < tid; ++i) {
                const float4 bi = vbox[i];            // LDS broadcast
                const float areai = (bi.z - bi.x + 1.0f) * (bi.w - bi.y + 1.0f);
                const float ltx = fmaxf(bi.x, bj.x);
                const float lty = fmaxf(bi.y, bj.y);
                const float rbx = fminf(bi.z, bj.z);
                const float rby = fminf(bi.w, bj.w);
                const float wq = fmaxf(rbx - ltx + 1.0f, 0.0f);
                const float hq = fmaxf(rby - lty + 1.0f, 0.0f);
                const float inter = wq * hq;
                const float iou = inter / (areai + areaj - inter);
                if (iou > NMS_THRESH) mymask |= (1ull << i);
            }
        }
        unsigned long long suppbits = 0ull;
        for (int i = 0; i < cnt; ++i) {
            if (!((suppbits >> i) & 1ull)) {
                const unsigned long long vote = __ballot((mymask >> i) & 1ull);
                suppbits |= vote;
            }
        }

        // popcount compaction (wave-uniform mask; c2 <= 64 < DET, no cap)
        unsigned long long kb = ~suppbits;
        if (cnt < 64) kb &= ((1ull << cnt) - 1ull);
        const int c2 = __popcll(kb);
        if (tid == 0) baseSh = atomicAdd(gK, c2);     // device-scope append
        __syncthreads();
        const int base = baseSh;

        if (tid < cnt && !((suppbits >> tid) & 1ull)) {
            const int kr = __popcll(kb & ((1ull << tid) - 1ull));
            const int slot = cls * DET + kr;
            const unsigned int bits = (unsigned int)(key[tid] >> 16);
            gkeys[base + kr] = ((unsigned long long)bits << 16) |
                               (unsigned long long)(65535 - slot);
            gboxes[base + kr] = vbox[tid];
        }
        return;
    }

    // ===================== SLOW PATH: cnt>64 (R6 verbatim) ===================
    int msz = 1;
    while (msz < cnt) msz <<= 1;
    for (int t = cnt + tid; t < msz; t += 64) key[t] = 0ull;
    __syncthreads();

    for (int k = 2; k <= msz; k <<= 1) {
        for (int jj = k >> 1; jj > 0; jj >>= 1) {
            for (int t = tid; t < msz; t += 64) {
                const int ixj = t ^ jj;
                if (ixj > t) {
                    const unsigned long long a = key[t], b = key[ixj];
                    const bool tAfter = (a < b);
                    const bool dirAsc = ((t & k) == 0);
                    if (dirAsc ? tAfter : !tAfter) { key[t] = b; key[ixj] = a; }
                }
            }
            __syncthreads();
        }
    }

    for (int t = tid; t < cnt; t += 64) {
        const int id = 1023 - (int)(key[t] & 0xFFFFull);
        const float4 p = ((const float4*)props)[id];
        const float w  = p.z - p.x + 1.0f;
        const float h  = p.w - p.y + 1.0f;
        const float cx = p.x + 0.5f * w;
        const float cy = p.y + 0.5f * h;

        const float4 r = ((const float4*)rel)[id * NC + (cls + 1)];
        const float dx = r.x / 10.0f;
        const float dy = r.y / 10.0f;
        const float dw = fminf(r.z / 5.0f, BBOX_CLIP);
        const float dh = fminf(r.w / 5.0f, BBOX_CLIP);

        const float pcx = dx * w + cx;
        const float pcy = dy * h + cy;
        const float pw  = expf(dw) * w;
        const float ph  = expf(dh) * h;

        float bx1 = pcx - 0.5f * pw;
        float by1 = pcy - 0.5f * ph;
        float bx2 = pcx + 0.5f * pw - 1.0f;
        float by2 = pcy + 0.5f * ph - 1.0f;

        bx1 = fminf(fmaxf(bx1, 0.0f), (float)(IMG_W - 1));
        bx2 = fminf(fmaxf(bx2, 0.0f), (float)(IMG_W - 1));
        by1 = fminf(fmaxf(by1, 0.0f), (float)(IMG_H - 1));
        by2 = fminf(fmaxf(by2, 0.0f), (float)(IMG_H - 1));

        vbox[t] = make_float4(bx1, by1, bx2, by2);
        supp[t] = 0;
    }
    __syncthreads();

    for (int i = 0; i < cnt; ++i) {
        if (!supp[i]) {
            const float4 bi = vbox[i];
            const float areai = (bi.z - bi.x + 1.0f) * (bi.w - bi.y + 1.0f);
            for (int t = i + 1 + tid; t < cnt; t += 64) {
                const float4 bj = vbox[t];
                const float areaj = (bj.z - bj.x + 1.0f) * (bj.w - bj.y + 1.0f);
                const float ltx = fmaxf(bi.x, bj.x);
                const float lty = fmaxf(bi.y, bj.y);
                const float rbx = fminf(bi.z, bj.z);
                const float rby = fminf(bi.w, bj.w);
                const float wq = fmaxf(rbx - ltx + 1.0f, 0.0f);
                const float hq = fmaxf(rby - lty + 1.0f, 0.0f);
                const float inter = wq * hq;
                const float iou = inter / (areai + areaj - inter);
                if (iou > NMS_THRESH) supp[t] = 1;
            }
        }
        __syncthreads();
    }

    if (tid == 0) {
        int c2 = 0;
        for (int r = 0; r < cnt && c2 < DET; ++r)
            if (!supp[r]) keptRank[c2++] = r;
        keptCnt = c2;
        baseSh = atomicAdd(gK, c2);
    }
    __syncthreads();

    const int kc = keptCnt, base = baseSh;
    for (int t = tid; t < kc; t += 64) {
        const int r = keptRank[t];
        const int slot = cls * DET + t;
        const unsigned int bits = (unsigned int)(key[r] >> 16);
        gkeys[base + t] = ((unsigned long long)bits << 16) |
                          (unsigned long long)(65535 - slot);
        gboxes[base + t] = vbox[r];
    }
}

// ---------------------------------------------------------------------------
// Kernel 3: rank-count top-DET over the K compacted candidates.
// 32 blocks x 256 threads, one candidate per thread. Staging: 4 independent
// loads per iteration, zero-fill tail (real keys nonzero -> pad rank-inert).
// Scan: LDS as ulonglong2, 8 independent ds_read_b128 = 16 keys per batch.
// Ranks dense & unique -> exactly one writer per output slot.
// ---------------------------------------------------------------------------
__global__ __launch_bounds__(256) void
topk_rank_kernel(const unsigned long long* __restrict__ gkeys,
                 const float4* __restrict__ gboxes,
                 const int* __restrict__ gK,
                 float* __restrict__ out) {
    const int K = *gK;
    if ((int)blockIdx.x * 256 >= K) return;

    __shared__ __align__(16) unsigned long long keysh[NCAND + 16];
    const int Kpad = (K + 15) & ~15;

    int t = threadIdx.x;
    for (; t + 768 < Kpad; t += 1024) {
        const unsigned long long a0 = (t       < K) ? gkeys[t]       : 0ull;
        const unsigned long long a1 = (t + 256 < K) ? gkeys[t + 256] : 0ull;
        const unsigned long long a2 = (t + 512 < K) ? gkeys[t + 512] : 0ull;
        const unsigned long long a3 = (t + 768 < K) ? gkeys[t + 768] : 0ull;
        keysh[t]       = a0;
        keysh[t + 256] = a1;
        keysh[t + 512] = a2;
        keysh[t + 768] = a3;
    }
    for (; t < Kpad; t += 256) keysh[t] = (t < K) ? gkeys[t] : 0ull;
    __syncthreads();

    const int g = blockIdx.x * 256 + threadIdx.x;
    if (g >= K) return;
    const unsigned long long my = keysh[g];

    const ulonglong2* kp = (const ulonglong2*)keysh;
    const int nb2 = Kpad >> 1;            // multiple of 8
    int rank = 0;
    for (int j = 0; j < nb2; j += 8) {
        ulonglong2 kk[8];
        #pragma unroll
        for (int u = 0; u < 8; ++u) kk[u] = kp[j + u];   // 8 indep ds_read_b128
        #pragma unroll
        for (int u = 0; u < 8; ++u) {
            rank += (kk[u].x > my) ? 1 : 0;
            rank += (kk[u].y > my) ? 1 : 0;
        }
    }

    if (rank < DET) {
        const float sc  = __uint_as_float((unsigned)(my >> 16));
        const int  slot = 65535 - (int)(my & 0xFFFFull);
        const float4 b = gboxes[g];
        out[rank * 4 + 0] = b.x;
        out[rank * 4 + 1] = b.y;
        out[rank * 4 + 2] = b.z;
        out[rank * 4 + 3] = b.w;
        out[4 * DET + rank] = sc;                       // score (>0 always)
        out[5 * DET + rank] = (float)(slot / DET + 1);  // label
    }
}

// ---------------------------------------------------------------------------
extern "C" void kernel_launch(void* const* d_in, const int* in_sizes, int n_in,
                              void* d_out, int out_size, void* d_ws, size_t ws_size,
                              hipStream_t stream) {
    (void)in_sizes; (void)n_in; (void)out_size; (void)ws_size;

    const float* class_logits   = (const float*)d_in[0];  // [NP, NC]
    const float* box_regression = (const float*)d_in[1];  // [NP, 4*NC]
    const float* proposals      = (const float*)d_in[2];  // [NP, 4]
    float* out = (float*)d_out;                           // 600 floats

    // Workspace layout (float units; all offsets 16B-aligned)
    float* ws        = (float*)d_ws;
    float* gboxes_f  = ws;                                    // NCAND*4 = 32000
    float* gkeys_f   = gboxes_f + (size_t)NCAND * 4;          // NCAND*2 = 16000
    float* scores_fg = gkeys_f + (size_t)NCAND * 2;           // CF*NP   = 81920
    int*   gK        = (int*)(scores_fg + (size_t)CF * NP);   // 1

    unsigned long long* gkeys = (unsigned long long*)gkeys_f;
    float4* gboxes = (float4*)gboxes_f;

    softmax_kernel<<<dim3(NP / 4), dim3(256), 0, stream>>>(
        class_logits, scores_fg, out, gK);

    class_nms_kernel<<<dim3(CF), dim3(64), 0, stream>>>(
        scores_fg, box_regression, proposals, gkeys, gboxes, gK);

    topk_rank_kernel<<<dim3((NCAND + 255) / 256), dim3(256), 0, stream>>>(
        gkeys, gboxes, gK, out);
}